// Round 2
// baseline (644.747 us; speedup 1.0000x reference)
//
#include <hip/hip_runtime.h>

#define ROWS 256
#define COLS 256
#define NP (ROWS*COLS)
#define BATCH 32

// f32 weight workspace layout (element offsets in d_ws)
#define WX_OFF 0      // 9 x 64
#define WH_OFF 576    // 16 x 64
#define B_OFF  1600   // 64
#define WO_OFF 1664   // 16 x 9
#define BO_OFF 1808   // 9
#define FLAG_OFF 1824 // int flag: 1 = inputs are f32, 0 = bf16

// d_out element offsets
#define OUT_DYN 0
#define OUT_LAT 2097152
#define OUT_H   18874368
#define OUT_C   52428800

using u16 = unsigned short;
using u32 = unsigned int;

__device__ __forceinline__ float bf2f(u16 v){ return __uint_as_float(((u32)v) << 16); }
__device__ __forceinline__ u16 f2bf(float f){
    u32 u = __float_as_uint(f);
    return (u16)((u + 0x7fffu + ((u >> 16) & 1u)) >> 16);   // RNE
}
__device__ __forceinline__ float rcpf_(float x){ return __builtin_amdgcn_rcpf(x); }
__device__ __forceinline__ float sigm(float x){ return rcpf_(1.f + __expf(-x)); }
__device__ __forceinline__ float tanh_(float x){ return 1.f - 2.f * rcpf_(1.f + __expf(2.f * x)); }
__device__ __forceinline__ void unpack2(u32 u, float& a, float& b){
    a = __uint_as_float(u << 16);
    b = __uint_as_float(u & 0xffff0000u);
}
__device__ __forceinline__ u32 pk2(float a, float b){
    return (u32)f2bf(a) | ((u32)f2bf(b) << 16);
}

// Single-block prep: detect input dtype from Wx bit patterns, then convert all
// weights to f32 in d_ws under the detected interpretation. Same work per call.
__global__ void prep_weights(const void* __restrict__ Wx, const void* __restrict__ Wh,
                             const void* __restrict__ b,  const void* __restrict__ Wo,
                             const void* __restrict__ bo, float* __restrict__ ws){
    __shared__ int sflag;
    const int t = threadIdx.x;
    if (t == 0) sflag = 0;
    __syncthreads();
    // Wx has 576 elements; read first 256 u16 words. bf16 data: |v| < 1 always.
    // f32 data: low-half words are ~uniform bits -> |v|>64 / NaN with p~0.48 each.
    float v = bf2f(((const u16*)Wx)[t]);
    if (!(fabsf(v) < 64.0f)) atomicOr(&sflag, 1);
    __syncthreads();
    const int f32in = sflag;

    for (int i = t; i < 576;  i += 256) ws[WX_OFF+i] = f32in ? ((const float*)Wx)[i] : bf2f(((const u16*)Wx)[i]);
    for (int i = t; i < 1024; i += 256) ws[WH_OFF+i] = f32in ? ((const float*)Wh)[i] : bf2f(((const u16*)Wh)[i]);
    for (int i = t; i < 64;   i += 256) ws[B_OFF+i]  = f32in ? ((const float*)b)[i]  : bf2f(((const u16*)b)[i]);
    for (int i = t; i < 144;  i += 256) ws[WO_OFF+i] = f32in ? ((const float*)Wo)[i] : bf2f(((const u16*)Wo)[i]);
    for (int i = t; i < 9;    i += 256) ws[BO_OFF+i] = f32in ? ((const float*)bo)[i] : bf2f(((const u16*)bo)[i]);
    if (t == 0) ((int*)ws)[FLAG_OFF] = f32in;
}

// One thread per (batch, cell). Block = one grid row (256 cols) of one batch.
__global__ __launch_bounds__(256) void lstm_step(
    const void* __restrict__ dyn_in,
    const void* __restrict__ lat_in,   // fallback at boundary cells only
    const void* __restrict__ lat_out,
    const void* __restrict__ h_in,
    const void* __restrict__ c_in,
    const float* __restrict__ W,       // f32 weights + flag in d_ws
    void* __restrict__ out)
{
    const int r   = blockIdx.x;
    const int bb  = blockIdx.y;
    const int col = threadIdx.x;
    const long base = (long)bb * NP + (long)r * COLS + col;
    const int f32in = ((const int*)W)[FLAG_OFF];   // block-uniform

    // 3 rows of pk_lat_out staged in LDS. f32: 3*256*8*4 = 24KB. bf16 uses half.
    __shared__ __align__(16) unsigned char latraw[3 * COLS * 8 * 4];

    const int drr[8] = {-1,-1,-1, 0, 0, 1, 1, 1};
    const int dcc[8] = {-1, 0, 1,-1, 1,-1, 0, 1};

    // ---- stage lat_out rows r-1..r+1 ----
    if (f32in){
        float* latf = (float*)latraw;
        #pragma unroll
        for (int rr = 0; rr < 3; rr++){
            int row = r + rr - 1;
            if (row >= 0 && row < ROWS){
                const uint4* s = (const uint4*)((const float*)lat_out + ((long)bb * NP + (long)row * COLS) * 8);
                uint4* d4 = (uint4*)(latf + (size_t)rr * COLS * 8);
                d4[col]       = s[col];
                d4[col + 256] = s[col + 256];
            }
        }
    } else {
        #pragma unroll
        for (int rr = 0; rr < 3; rr++){
            int row = r + rr - 1;
            if (row >= 0 && row < ROWS){
                const uint4* s = (const uint4*)((const u16*)lat_out + ((long)bb * NP + (long)row * COLS) * 8);
                ((uint4*)latraw)[rr * COLS + col] = s[col];
            }
        }
    }
    __syncthreads();

    // ---- gather x = [dyn, lateral(8)] and load h, c ----
    float x[9], hv[16], cv[16];
    if (f32in){
        const float* latf = (const float*)latraw;
        x[0] = ((const float*)dyn_in)[base];
        #pragma unroll
        for (int d = 0; d < 8; d++){
            int nr = r + drr[d], nc = col + dcc[d];
            if (nr >= 0 && nr < ROWS && nc >= 0 && nc < COLS)
                x[1 + d] = latf[((drr[d] + 1) * COLS + nc) * 8 + d];
            else
                x[1 + d] = ((const float*)lat_in)[base * 8 + d];
        }
        const float4* hp = (const float4*)h_in + base * 4;
        const float4* cp = (const float4*)c_in + base * 4;
        #pragma unroll
        for (int q = 0; q < 4; q++){
            float4 hq = hp[q], cq = cp[q];
            hv[4*q+0]=hq.x; hv[4*q+1]=hq.y; hv[4*q+2]=hq.z; hv[4*q+3]=hq.w;
            cv[4*q+0]=cq.x; cv[4*q+1]=cq.y; cv[4*q+2]=cq.z; cv[4*q+3]=cq.w;
        }
    } else {
        const u16* lat = (const u16*)latraw;
        x[0] = bf2f(((const u16*)dyn_in)[base]);
        #pragma unroll
        for (int d = 0; d < 8; d++){
            int nr = r + drr[d], nc = col + dcc[d];
            if (nr >= 0 && nr < ROWS && nc >= 0 && nc < COLS)
                x[1 + d] = bf2f(lat[((drr[d] + 1) * COLS + nc) * 8 + d]);
            else
                x[1 + d] = bf2f(((const u16*)lat_in)[base * 8 + d]);
        }
        const uint4* hp = (const uint4*)h_in + base * 2;
        const uint4* cp = (const uint4*)c_in + base * 2;
        uint4 h0 = hp[0], h1 = hp[1], c0 = cp[0], c1 = cp[1];
        unpack2(h0.x, hv[0], hv[1]);  unpack2(h0.y, hv[2], hv[3]);
        unpack2(h0.z, hv[4], hv[5]);  unpack2(h0.w, hv[6], hv[7]);
        unpack2(h1.x, hv[8], hv[9]);  unpack2(h1.y, hv[10], hv[11]);
        unpack2(h1.z, hv[12], hv[13]);unpack2(h1.w, hv[14], hv[15]);
        unpack2(c0.x, cv[0], cv[1]);  unpack2(c0.y, cv[2], cv[3]);
        unpack2(c0.z, cv[4], cv[5]);  unpack2(c0.w, cv[6], cv[7]);
        unpack2(c1.x, cv[8], cv[9]);  unpack2(c1.y, cv[10], cv[11]);
        unpack2(c1.z, cv[12], cv[13]);unpack2(c1.w, cv[14], cv[15]);
    }

    // ---- gates = x @ Wx + h @ Wh + b (weights via uniform s_load) ----
    float acc[64];
    #pragma unroll
    for (int j = 0; j < 64; j++) acc[j] = W[B_OFF + j];
    #pragma unroll
    for (int m = 0; m < 9; m++){
        float xm = x[m];
        #pragma unroll
        for (int j = 0; j < 64; j++) acc[j] = fmaf(xm, W[WX_OFF + m * 64 + j], acc[j]);
    }
    #pragma unroll
    for (int m = 0; m < 16; m++){
        float hm = hv[m];
        #pragma unroll
        for (int j = 0; j < 64; j++) acc[j] = fmaf(hm, W[WH_OFF + m * 64 + j], acc[j]);
    }

    // ---- LSTM pointwise + fused h_new @ Wo ----
    float oacc[9];
    #pragma unroll
    for (int t = 0; t < 9; t++) oacc[t] = W[BO_OFF + t];
    float hn[16], cn[16];
    #pragma unroll
    for (int k = 0; k < 16; k++){
        float ig = sigm(acc[k]);
        float fg = sigm(acc[16 + k]);
        float gg = tanh_(acc[32 + k]);
        float og = sigm(acc[48 + k]);
        float c2 = fmaf(fg, cv[k], ig * gg);
        float h2 = og * tanh_(c2);
        cn[k] = c2; hn[k] = h2;
        #pragma unroll
        for (int t = 0; t < 9; t++) oacc[t] = fmaf(h2, W[WO_OFF + k * 9 + t], oacc[t]);
    }
    float dynout = tanh_(oacc[0]);
    float ov[8];
    #pragma unroll
    for (int t = 0; t < 8; t++) ov[t] = tanh_(oacc[1 + t]);

    // ---- store ----
    if (f32in){
        float* of = (float*)out;
        of[OUT_DYN + base] = dynout;
        float4* lp = (float4*)(of + OUT_LAT) + base * 2;
        lp[0] = make_float4(ov[0], ov[1], ov[2], ov[3]);
        lp[1] = make_float4(ov[4], ov[5], ov[6], ov[7]);
        float4* hp2 = (float4*)(of + OUT_H) + base * 4;
        float4* cp2 = (float4*)(of + OUT_C) + base * 4;
        #pragma unroll
        for (int q = 0; q < 4; q++){
            hp2[q] = make_float4(hn[4*q], hn[4*q+1], hn[4*q+2], hn[4*q+3]);
            cp2[q] = make_float4(cn[4*q], cn[4*q+1], cn[4*q+2], cn[4*q+3]);
        }
    } else {
        u16* ob = (u16*)out;
        ob[OUT_DYN + base] = f2bf(dynout);
        *((uint4*)(ob + OUT_LAT) + base) =
            make_uint4(pk2(ov[0], ov[1]), pk2(ov[2], ov[3]), pk2(ov[4], ov[5]), pk2(ov[6], ov[7]));
        uint4* hop = (uint4*)(ob + OUT_H) + base * 2;
        hop[0] = make_uint4(pk2(hn[0], hn[1]), pk2(hn[2], hn[3]), pk2(hn[4], hn[5]), pk2(hn[6], hn[7]));
        hop[1] = make_uint4(pk2(hn[8], hn[9]), pk2(hn[10], hn[11]), pk2(hn[12], hn[13]), pk2(hn[14], hn[15]));
        uint4* cop = (uint4*)(ob + OUT_C) + base * 2;
        cop[0] = make_uint4(pk2(cn[0], cn[1]), pk2(cn[2], cn[3]), pk2(cn[4], cn[5]), pk2(cn[6], cn[7]));
        cop[1] = make_uint4(pk2(cn[8], cn[9]), pk2(cn[10], cn[11]), pk2(cn[12], cn[13]), pk2(cn[14], cn[15]));
    }
}

extern "C" void kernel_launch(void* const* d_in, const int* in_sizes, int n_in,
                              void* d_out, int out_size, void* d_ws, size_t ws_size,
                              hipStream_t stream){
    const void* dyn  = d_in[0];
    const void* lin  = d_in[1];
    const void* lout = d_in[2];
    const void* h    = d_in[3];
    const void* c    = d_in[4];
    const void* Wx   = d_in[5];
    const void* Wh   = d_in[6];
    const void* b    = d_in[7];
    const void* Wo   = d_in[8];
    const void* bo   = d_in[9];
    float* ws = (float*)d_ws;

    hipLaunchKernelGGL(prep_weights, dim3(1), dim3(256), 0, stream, Wx, Wh, b, Wo, bo, ws);
    hipLaunchKernelGGL(lstm_step, dim3(ROWS, BATCH), dim3(256), 0, stream,
                       dyn, lin, lout, h, c, ws, d_out);
}